// Round 25
// baseline (210.287 us; speedup 1.0000x reference)
//
#include <hip/hip_runtime.h>
#include <hip/hip_bf16.h>

#define Bn  512
#define Sn  30
#define Dm  300
#define Hn  20
#define DHn 20
#define AHn 200
#define HDn 400
#define EQn 6000
#define KP  320           // GEMM K padded to 10*32
#define NW  6400          // N = 6000 (Wq) + 400 (Wv) = 50*128 exactly
#define KB  328           // kb/kT row stride (bf16)
#define CFS 304           // cf LDS row stride in k_ckt
#define AHP 208           // WV rows padded to 13*16
#define KWV 416           // WV cols padded to 13*32

typedef __attribute__((ext_vector_type(8))) short short8;
typedef __attribute__((ext_vector_type(4))) short short4v;
typedef __attribute__((ext_vector_type(4))) float f32x4;

__device__ __forceinline__ unsigned short f2b(float v) {
    __hip_bfloat16 h = __float2bfloat16(v);
    return *(unsigned short*)&h;
}
__device__ __forceinline__ float b2f(unsigned short u) {
    union { unsigned int i; float f; } cv; cv.i = ((unsigned int)u) << 16; return cv.f;
}
// async global->LDS, 16B per lane; dest = wave-uniform base + lane*16
__device__ __forceinline__ void gload_lds16(const void* g, void* l) {
    __builtin_amdgcn_global_load_lds(
        (__attribute__((address_space(1))) void*)(void*)(g),
        (__attribute__((address_space(3))) void*)(l), 16, 0, 0u);
}

// ---------------------------------------------------------------------------
// k_ckt: one block per bl. Computes c = emb[x]+PE as bf16 in LDS, then writes
//   (a) cbf[(bl*30+s)*320 + d] (zero-padded K) and
//   (b) kT[bl][j*KB + d] = c_flat[d*30+j] (pre-transposed, padded).
// Replaces the old k_c + k_kt pair (saves a dispatch + cbf re-fetch).
// ---------------------------------------------------------------------------
__global__ __launch_bounds__(256) void k_ckt(const int* __restrict__ x,
        const float* __restrict__ emb, unsigned short* __restrict__ cbf,
        unsigned short* __restrict__ kT, int b0)
{
    __shared__ __attribute__((aligned(16))) unsigned short cf[Sn * CFS];
    int bl = blockIdx.x, t = threadIdx.x;

    // compute c (bf16) into LDS
    for (int p = t; p < Sn * Dm; p += 256) {
        int s = p / Dm, d = p - s * Dm;
        int tok = x[(b0 + bl) * Sn + s];
        float dv = expf(-0.06140226914650789f * (float)(d >> 1));
        float ang = (float)s * dv;
        float val = emb[(size_t)tok * Dm + d] + ((d & 1) ? cosf(ang) : sinf(ang));
        cf[s * CFS + d] = f2b(val);
    }
    __syncthreads();

    // write cbf rows (30 x 40 short8-chunks; cols 300..319 zero)
    for (int p = t; p < 30 * 40; p += 256) {
        int s = p / 40, un = p % 40, d0 = un * 8;
        short8 v = {0, 0, 0, 0, 0, 0, 0, 0};
        #pragma unroll
        for (int e = 0; e < 8; ++e) {
            int d = d0 + e;
            if (d < Dm) v[e] = (short)cf[s * CFS + d];
        }
        *(short8*)&cbf[(size_t)(bl * Sn + s) * KP + d0] = v;
    }

    // write kT: 32 rows x 41 short8-chunks; K(d,j) = c_flat[d*30+j]
    for (int p = t; p < 1312; p += 256) {
        int j = p / 41, ch = p % 41, d0 = ch * 8;
        short8 v = {0, 0, 0, 0, 0, 0, 0, 0};
        if (j < Sn) {
            #pragma unroll
            for (int e = 0; e < 8; ++e) {
                int d = d0 + e;
                if (d < Dm) {
                    int f = d * Sn + j;
                    v[e] = (short)cf[(f / Dm) * CFS + (f % Dm)];
                }
            }
        }
        *(short8*)&kT[(size_t)bl * (32 * KB) + j * KB + d0] = v;
    }
}

// ---------------------------------------------------------------------------
// k_cast_w: Wb[NW][KP] = bf16([Wq; Wv]); WVb[AHP][KWV] = bf16(WV), zero-padded
// ---------------------------------------------------------------------------
__global__ __launch_bounds__(256) void k_cast_w(const float* __restrict__ Wq,
        const float* __restrict__ Wv, const float* __restrict__ WVm,
        unsigned short* __restrict__ Wb, unsigned short* __restrict__ WVb)
{
    int total = NW * KP + AHP * KWV;
    for (int p = blockIdx.x * 256 + threadIdx.x; p < total; p += gridDim.x * 256) {
        if (p < NW * KP) {
            int nq = p / KP, k = p - nq * KP;
            float v = 0.f;
            if (k < Dm)
                v = (nq < EQn) ? Wq[(size_t)nq * Dm + k]
                               : Wv[(size_t)(nq - EQn) * Dm + k];
            Wb[p] = f2b(v);
        } else {
            int q = p - NW * KP;
            int u = q / KWV, k = q - u * KWV;
            float v = (u < AHn && k < HDn) ? WVm[(size_t)u * HDn + k] : 0.f;
            WVb[q] = f2b(v);
        }
    }
}

// ---------------------------------------------------------------------------
// k_xqm (R23-verified): [xqb | xvb] = bf16(cbf @ Wb^T + bias), 128x128 tile,
// 4 waves, BK=64 double-buffer, both-sides XOR swizzle, nt output stores.
// ---------------------------------------------------------------------------
__global__ __launch_bounds__(256) void k_xqm(const unsigned short* __restrict__ Ab,
        const unsigned short* __restrict__ Bb, const float* __restrict__ bq,
        const float* __restrict__ bv, unsigned short* __restrict__ xqb,
        unsigned short* __restrict__ xvb, int Mloc, int mtiles)
{
    __shared__ __attribute__((aligned(16))) char smem[65536];
    unsigned short (*Cs)[136] = (unsigned short (*)[136])smem;   // epilogue alias

    int nwg = 50 * mtiles;
    int bid = blockIdx.x;
    int q8 = nwg >> 3, r8 = nwg & 7;
    int xcd = bid & 7, idx = bid >> 3;
    int wg = (xcd < r8 ? xcd * (q8 + 1) : r8 * (q8 + 1) + (xcd - r8) * q8) + idx;
    int bx = wg % 50, by = wg / 50;

    int t = threadIdx.x;
    int l = t & 63, w = t >> 6;
    int wm = w >> 1, wn = w & 1;
    int m0 = by * 128, n0 = bx * 128;
    int cl = l & 15, rh = l >> 4;

    int srow = l >> 3;                 // row&7 within chunk
    int sun  = (l & 7) ^ srow;         // inverse-swizzled source col-unit
    int sx = cl & 7;                   // fragment-read row&7

    f32x4 zero4 = {0.f, 0.f, 0.f, 0.f};
    f32x4 acc[4][4];
    #pragma unroll
    for (int a = 0; a < 4; ++a)
        #pragma unroll
        for (int bb = 0; bb < 4; ++bb) acc[a][bb] = zero4;

    #pragma unroll
    for (int i = 0; i < 4; ++i) {
        int c = w * 4 + i;
        int row = c * 8 + srow;
        gload_lds16(&Ab[(size_t)(m0 + row) * KP + 0 + sun * 8], smem + c * 1024);
        gload_lds16(&Bb[(size_t)(n0 + row) * KP + 0 + sun * 8], smem + 16384 + c * 1024);
    }
    __syncthreads();

    int cur = 0;
    #pragma unroll
    for (int step = 0; step < 5; ++step) {
        if (step < 4) {
            int k0 = (step + 1) * 64;
            char* nb = smem + (cur ^ 1) * 32768;
            #pragma unroll
            for (int i = 0; i < 4; ++i) {
                int c = w * 4 + i;
                int row = c * 8 + srow;
                gload_lds16(&Ab[(size_t)(m0 + row) * KP + k0 + sun * 8], nb + c * 1024);
                gload_lds16(&Bb[(size_t)(n0 + row) * KP + k0 + sun * 8], nb + 16384 + c * 1024);
            }
        }
        {
            unsigned short (*As)[64] = (unsigned short (*)[64])(smem + cur * 32768);
            unsigned short (*Bs)[64] = (unsigned short (*)[64])(smem + cur * 32768 + 16384);
            #pragma unroll
            for (int k2 = 0; k2 < 2; ++k2) {
                int ku = ((k2 * 4 + rh) ^ sx) * 8;
                short8 af[4], bf[4];
                #pragma unroll
                for (int f = 0; f < 4; ++f) {
                    af[f] = *(const short8*)&As[wm * 64 + f * 16 + cl][ku];
                    bf[f] = *(const short8*)&Bs[wn * 64 + f * 16 + cl][ku];
                }
                #pragma unroll
                for (int mf = 0; mf < 4; ++mf)
                    #pragma unroll
                    for (int nf = 0; nf < 4; ++nf)
                        acc[mf][nf] = __builtin_amdgcn_mfma_f32_16x16x32_bf16(
                            af[mf], bf[nf], acc[mf][nf], 0, 0, 0);
            }
        }
        __syncthreads();
        cur ^= 1;
    }

    #pragma unroll
    for (int nf = 0; nf < 4; ++nf) {
        int gn = n0 + wn * 64 + nf * 16 + cl;
        float bias = (gn < EQn) ? bq[gn] : bv[gn - EQn];
        #pragma unroll
        for (int mf = 0; mf < 4; ++mf) {
            int lrow = wm * 64 + mf * 16 + rh * 4;
            #pragma unroll
            for (int r = 0; r < 4; ++r)
                Cs[lrow + r][wn * 64 + nf * 16 + cl] = f2b(acc[mf][nf][r] + bias);
        }
    }
    __syncthreads();

    for (int ch = t; ch < 128 * 16; ch += 256) {
        int row = ch >> 4, colc = (ch & 15) * 8;
        int gm = m0 + row;
        short8 v = *(const short8*)&Cs[row][colc];
        int gn = n0 + colc;
        if (gn < EQn)
            __builtin_nontemporal_store(v, (short8*)&xqb[(size_t)gm * EQn + gn]);
        else
            __builtin_nontemporal_store(v, (short8*)&xvb[(size_t)gm * HDn + (gn - EQn)]);
    }
}

// ---------------------------------------------------------------------------
// k_attn v5: WAVE = HEAD. Block = (bl, head-group of 4). 5 blocks per bl.
// ---------------------------------------------------------------------------
__global__ __launch_bounds__(256) void k_attn(const unsigned short* __restrict__ kT,
        const unsigned short* __restrict__ xqb, const unsigned short* __restrict__ xvb,
        float* __restrict__ h2, int nwg)
{
    __shared__ __attribute__((aligned(16))) unsigned short kb[32 * KB];
    __shared__ float wmw[4][32 * 33];
    __shared__ float vmw[4][Sn * DHn];

    int t = threadIdx.x, l = t & 63, w = t >> 6;
    int cl = l & 15, rh = l >> 4;

    int bid = blockIdx.x;
    int q8 = nwg >> 3, r8 = nwg & 7;
    int xcd = bid & 7, idx = bid >> 3;
    int wg = (xcd < r8 ? xcd * (q8 + 1) : r8 * (q8 + 1) + (xcd - r8) * q8) + idx;
    int bl = wg / 5, hg = wg % 5;
    int h = hg * 4 + w;

    for (int p = t; p < 1312; p += 256)
        *(short8*)&kb[p * 8] = *(const short8*)&kT[(size_t)bl * (32 * KB) + p * 8];

    const unsigned short* vsrc = xvb + (size_t)bl * (Sn * HDn) + h * (Sn * DHn);
    for (int ch = l; ch < 75; ch += 64) {
        short8 v = *(const short8*)&vsrc[ch * 8];
        #pragma unroll
        for (int e = 0; e < 8; ++e) vmw[w][ch * 8 + e] = b2f((unsigned short)v[e]);
    }

    const unsigned short* qsrc = xqb + (size_t)bl * (Sn * EQn) + (size_t)h * (Sn * Dm);
    short8 aq[2][10];
    #pragma unroll
    for (int ti = 0; ti < 2; ++ti) {
        int row = ti * 16 + cl; if (row > 29) row = 29;
        const unsigned short* qrow = qsrc + row * Dm;
        #pragma unroll
        for (int ks = 0; ks < 9; ++ks)
            aq[ti][ks] = *(const short8*)&qrow[ks * 32 + rh * 8];
        short8 a9 = {0, 0, 0, 0, 0, 0, 0, 0};
        if (rh == 0) a9 = *(const short8*)&qrow[288];
        else if (rh == 1) {
            short4v lo = *(const short4v*)&qrow[296];
            a9[0] = lo.x; a9[1] = lo.y; a9[2] = lo.z; a9[3] = lo.w;
        }
        aq[ti][9] = a9;
    }
    __syncthreads();

    f32x4 zero4 = {0.f, 0.f, 0.f, 0.f};
    f32x4 acc[2][2] = {{zero4, zero4}, {zero4, zero4}};
    #pragma unroll
    for (int ks = 0; ks < 10; ++ks) {
        short8 b0 = *(const short8*)&kb[cl * KB + ks * 32 + rh * 8];
        short8 b1 = *(const short8*)&kb[(16 + cl) * KB + ks * 32 + rh * 8];
        #pragma unroll
        for (int ti = 0; ti < 2; ++ti) {
            acc[ti][0] = __builtin_amdgcn_mfma_f32_16x16x32_bf16(aq[ti][ks], b0, acc[ti][0], 0, 0, 0);
            acc[ti][1] = __builtin_amdgcn_mfma_f32_16x16x32_bf16(aq[ti][ks], b1, acc[ti][1], 0, 0, 0);
        }
    }

    float m0 = -1e30f, m1 = -1e30f;
    #pragma unroll
    for (int ti = 0; ti < 2; ++ti)
        #pragma unroll
        for (int r = 0; r < 4; ++r) {
            int i = ti * 16 + rh * 4 + r;
            if (i < Sn) { m0 = fmaxf(m0, acc[ti][0][r]); m1 = fmaxf(m1, acc[ti][1][r]); }
        }
    m0 = fmaxf(m0, __shfl_xor(m0, 16)); m0 = fmaxf(m0, __shfl_xor(m0, 32));
    m1 = fmaxf(m1, __shfl_xor(m1, 16)); m1 = fmaxf(m1, __shfl_xor(m1, 32));

    float e0[2][4], e1[2][4], s0 = 0.f, s1 = 0.f;
    #pragma unroll
    for (int ti = 0; ti < 2; ++ti)
        #pragma unroll
        for (int r = 0; r < 4; ++r) {
            int i = ti * 16 + rh * 4 + r;
            float v0 = 0.f, v1 = 0.f;
            if (i < Sn) {
                v0 = __expf(acc[ti][0][r] - m0);
                v1 = __expf(acc[ti][1][r] - m1);
            }
            e0[ti][r] = v0; e1[ti][r] = v1;
            s0 += v0; s1 += v1;
        }
    s0 += __shfl_xor(s0, 16); s0 += __shfl_xor(s0, 32);
    s1 += __shfl_xor(s1, 16); s1 += __shfl_xor(s1, 32);
    float inv0 = 1.f / s0, inv1 = 1.f / s1;

    #pragma unroll
    for (int ti = 0; ti < 2; ++ti)
        #pragma unroll
        for (int r = 0; r < 4; ++r) {
            int i = ti * 16 + rh * 4 + r;
            if (i < Sn) {
                wmw[w][i * 33 + cl] = e0[ti][r] * inv0;
                if (cl < 14) wmw[w][i * 33 + 16 + cl] = e1[ti][r] * inv1;
            }
        }

    for (int p = l; p < Sn * DHn; p += 64) {
        int i = p / DHn, k = p - i * DHn;
        float a = 0.f;
        #pragma unroll
        for (int j = 0; j < Sn; ++j) a += wmw[w][i * 33 + j] * vmw[w][j * DHn + k];
        h2[(size_t)bl * (Sn * HDn) + h * (Sn * DHn) + p] = a;
    }
}

// ---------------------------------------------------------------------------
// k_pool v2: per bl. MFMA score GEMM + exact f32 weighted sum. (R23-verified)
// ---------------------------------------------------------------------------
__global__ __launch_bounds__(256) void k_pool(const float* __restrict__ h2,
        const unsigned short* __restrict__ WVb, const float* __restrict__ bV,
        const float* __restrict__ wq2, const float* __restrict__ bq2,
        float* __restrict__ out, int b0)
{
    __shared__ __attribute__((aligned(16))) float hb[Sn * HDn];
    __shared__ __attribute__((aligned(16))) unsigned short hbf[32 * 424];
    __shared__ float zp[4][32];
    __shared__ float psm[Sn];
    int bl = blockIdx.x, t = threadIdx.x;
    int l = t & 63, w = t >> 6;
    int cl = l & 15, rh = l >> 4;

    for (int i = t; i < Sn * HDn; i += 256) hb[i] = h2[(size_t)bl * (Sn * HDn) + i];
    __syncthreads();
    for (int p = t; p < 32 * 424; p += 256) {
        int row = p / 424, col = p - row * 424;
        unsigned short v = 0;
        if (row < Sn && col < HDn) v = f2b(hb[row * HDn + col]);
        hbf[p] = v;
    }
    __syncthreads();

    float zacc[2][4] = {{0.f,0.f,0.f,0.f},{0.f,0.f,0.f,0.f}};
    for (int nt = w; nt < 13; nt += 4) {
        int u0 = nt * 16;
        f32x4 acc0 = {0.f,0.f,0.f,0.f}, acc1 = {0.f,0.f,0.f,0.f};
        const unsigned short* brow = &WVb[(size_t)(u0 + cl) * KWV];
        #pragma unroll
        for (int ks = 0; ks < 13; ++ks) {
            short8 b  = *(const short8*)&brow[ks * 32 + rh * 8];
            short8 a0 = *(const short8*)&hbf[cl * 424 + ks * 32 + rh * 8];
            short8 a1 = *(const short8*)&hbf[(16 + cl) * 424 + ks * 32 + rh * 8];
            acc0 = __builtin_amdgcn_mfma_f32_16x16x32_bf16(a0, b, acc0, 0, 0, 0);
            acc1 = __builtin_amdgcn_mfma_f32_16x16x32_bf16(a1, b, acc1, 0, 0, 0);
        }
        int u = u0 + cl;
        float bVu = (u < AHn) ? bV[u] : 0.f;
        float wqu = (u < AHn) ? wq2[u] : 0.f;
        #pragma unroll
        for (int r = 0; r < 4; ++r) {
            zacc[0][r] += tanhf(acc0[r] + bVu) * wqu;
            zacc[1][r] += tanhf(acc1[r] + bVu) * wqu;
        }
    }
    #pragma unroll
    for (int mt = 0; mt < 2; ++mt)
        #pragma unroll
        for (int r = 0; r < 4; ++r) {
            float v = zacc[mt][r];
            v += __shfl_xor(v, 1); v += __shfl_xor(v, 2);
            v += __shfl_xor(v, 4); v += __shfl_xor(v, 8);
            zacc[mt][r] = v;
        }
    if (cl == 0) {
        #pragma unroll
        for (int mt = 0; mt < 2; ++mt)
            #pragma unroll
            for (int r = 0; r < 4; ++r)
                zp[w][mt * 16 + rh * 4 + r] = zacc[mt][r];
    }
    __syncthreads();

    if (t == 0) {
        float b2 = bq2[0];
        float sc[Sn], mx = -1e30f;
        for (int s = 0; s < Sn; ++s) {
            sc[s] = zp[0][s] + zp[1][s] + zp[2][s] + zp[3][s] + b2;
            mx = fmaxf(mx, sc[s]);
        }
        float sum = 0.f;
        for (int s = 0; s < Sn; ++s) { float e = __expf(sc[s] - mx); psm[s] = e; sum += e; }
        float inv = 1.f / sum;
        for (int s = 0; s < Sn; ++s) psm[s] *= inv;
    }
    __syncthreads();
    for (int e = t; e < HDn; e += 256) {
        float z = 0.f;
        #pragma unroll
        for (int s = 0; s < Sn; ++s) z += psm[s] * hb[s * HDn + e];
        out[(size_t)(b0 + bl) * HDn + e] = z;
    }
}

// ---------------------------------------------------------------------------
extern "C" void kernel_launch(void* const* d_in, const int* in_sizes, int n_in,
                              void* d_out, int out_size, void* d_ws, size_t ws_size,
                              hipStream_t stream)
{
    const int*   x   = (const int*)d_in[0];
    const float* emb = (const float*)d_in[1];
    const float* Wq  = (const float*)d_in[2];
    const float* bq  = (const float*)d_in[3];
    const float* Wv  = (const float*)d_in[4];
    const float* bv  = (const float*)d_in[5];
    const float* WVm = (const float*)d_in[6];
    const float* bV  = (const float*)d_in[7];
    const float* wq2 = (const float*)d_in[8];
    const float* bq2 = (const float*)d_in[9];
    float* outp = (float*)d_out;

    const size_t wbBytes  = (size_t)NW * KP * 2;            // 4,096,000
    const size_t wvbBytes = (size_t)AHP * KWV * 2;          //   173,056
    size_t fixed = wbBytes + wvbBytes;
    size_t wrem = (ws_size > fixed) ? ws_size - fixed : 0;
    int CB = Bn;                                            // prefer ONE chunk
    while (CB > 64 && (size_t)CB * 472192ull > wrem) CB >>= 1;

    char* ws = (char*)d_ws;
    unsigned short* Wb  = (unsigned short*)(ws);
    unsigned short* WVb = (unsigned short*)(ws + wbBytes);
    char* wsc = ws + fixed;
    unsigned short* cbf = (unsigned short*)(wsc);
    unsigned short* xqb = (unsigned short*)(wsc + (size_t)CB * 19200ull);
    unsigned short* xvb = (unsigned short*)(wsc + (size_t)CB * 379200ull);
    unsigned short* kT  = (unsigned short*)(wsc + (size_t)CB * 403200ull);
    float*          h2  = (float*)(wsc + (size_t)CB * 424192ull);

    k_cast_w<<<dim3(2048), dim3(256), 0, stream>>>(Wq, Wv, WVm, Wb, WVb);

    for (int b0 = 0; b0 < Bn; b0 += CB) {
        int nloc = (b0 + CB <= Bn) ? CB : (Bn - b0);
        int Mloc = nloc * Sn;
        int mtiles = (Mloc + 127) / 128;
        k_ckt<<<dim3(nloc), dim3(256), 0, stream>>>(x, emb, cbf, kT, b0);
        k_xqm<<<dim3(50 * mtiles), dim3(256), 0, stream>>>(cbf, Wb, bq, bv,
                                                           xqb, xvb, Mloc, mtiles);
        int nwg = nloc * 5;
        k_attn<<<dim3(nwg), dim3(256), 0, stream>>>(kT, xqb, xvb, h2, nwg);
        k_pool<<<dim3(nloc), dim3(256), 0, stream>>>(h2, WVb, bV, wq2, bq2, outp, b0);
    }
}

// Round 26
// 205.277 us; speedup vs baseline: 1.0244x; 1.0244x over previous
//
#include <hip/hip_runtime.h>
#include <hip/hip_bf16.h>

#define Bn  512
#define Sn  30
#define Dm  300
#define Hn  20
#define DHn 20
#define AHn 200
#define HDn 400
#define EQn 6000
#define KP  320           // GEMM K padded to 10*32
#define NW  6400          // N = 6000 (Wq) + 400 (Wv) = 50*128 exactly
#define KB  328           // kb/kT row stride (bf16)
#define CFS 304           // cf LDS row stride in k_ckt
#define AHP 208           // WV rows padded to 13*16
#define KWV 416           // WV cols padded to 13*32

typedef __attribute__((ext_vector_type(8))) short short8;
typedef __attribute__((ext_vector_type(4))) short short4v;
typedef __attribute__((ext_vector_type(4))) float f32x4;

__device__ __forceinline__ unsigned short f2b(float v) {
    __hip_bfloat16 h = __float2bfloat16(v);
    return *(unsigned short*)&h;
}
__device__ __forceinline__ float b2f(unsigned short u) {
    union { unsigned int i; float f; } cv; cv.i = ((unsigned int)u) << 16; return cv.f;
}
// async global->LDS, 16B per lane; dest = wave-uniform base + lane*16
__device__ __forceinline__ void gload_lds16(const void* g, void* l) {
    __builtin_amdgcn_global_load_lds(
        (__attribute__((address_space(1))) void*)(void*)(g),
        (__attribute__((address_space(3))) void*)(l), 16, 0, 0u);
}

// ---------------------------------------------------------------------------
// k_ckt: one block per bl. c = emb[x]+PE (bf16, LDS) -> cbf rows + kT transposed
// ---------------------------------------------------------------------------
__global__ __launch_bounds__(256) void k_ckt(const int* __restrict__ x,
        const float* __restrict__ emb, unsigned short* __restrict__ cbf,
        unsigned short* __restrict__ kT, int b0)
{
    __shared__ __attribute__((aligned(16))) unsigned short cf[Sn * CFS];
    int bl = blockIdx.x, t = threadIdx.x;

    for (int p = t; p < Sn * Dm; p += 256) {
        int s = p / Dm, d = p - s * Dm;
        int tok = x[(b0 + bl) * Sn + s];
        float dv = expf(-0.06140226914650789f * (float)(d >> 1));
        float ang = (float)s * dv;
        float val = emb[(size_t)tok * Dm + d] + ((d & 1) ? cosf(ang) : sinf(ang));
        cf[s * CFS + d] = f2b(val);
    }
    __syncthreads();

    for (int p = t; p < 30 * 40; p += 256) {
        int s = p / 40, un = p % 40, d0 = un * 8;
        short8 v = {0, 0, 0, 0, 0, 0, 0, 0};
        #pragma unroll
        for (int e = 0; e < 8; ++e) {
            int d = d0 + e;
            if (d < Dm) v[e] = (short)cf[s * CFS + d];
        }
        *(short8*)&cbf[(size_t)(bl * Sn + s) * KP + d0] = v;
    }

    for (int p = t; p < 1312; p += 256) {
        int j = p / 41, ch = p % 41, d0 = ch * 8;
        short8 v = {0, 0, 0, 0, 0, 0, 0, 0};
        if (j < Sn) {
            #pragma unroll
            for (int e = 0; e < 8; ++e) {
                int d = d0 + e;
                if (d < Dm) {
                    int f = d * Sn + j;
                    v[e] = (short)cf[(f / Dm) * CFS + (f % Dm)];
                }
            }
        }
        *(short8*)&kT[(size_t)bl * (32 * KB) + j * KB + d0] = v;
    }
}

// ---------------------------------------------------------------------------
// k_cast_w: Wb[NW][KP] = bf16([Wq; Wv]); WVb[AHP][KWV] = bf16(WV), zero-padded
// ---------------------------------------------------------------------------
__global__ __launch_bounds__(256) void k_cast_w(const float* __restrict__ Wq,
        const float* __restrict__ Wv, const float* __restrict__ WVm,
        unsigned short* __restrict__ Wb, unsigned short* __restrict__ WVb)
{
    int total = NW * KP + AHP * KWV;
    for (int p = blockIdx.x * 256 + threadIdx.x; p < total; p += gridDim.x * 256) {
        if (p < NW * KP) {
            int nq = p / KP, k = p - nq * KP;
            float v = 0.f;
            if (k < Dm)
                v = (nq < EQn) ? Wq[(size_t)nq * Dm + k]
                               : Wv[(size_t)(nq - EQn) * Dm + k];
            Wb[p] = f2b(v);
        } else {
            int q = p - NW * KP;
            int u = q / KWV, k = q - u * KWV;
            float v = (u < AHn && k < HDn) ? WVm[(size_t)u * HDn + k] : 0.f;
            WVb[q] = f2b(v);
        }
    }
}

// ---------------------------------------------------------------------------
// k_xqm v7: 128x128 tile, BK=64 dbuf, both-sides XOR swizzle, nt-stores,
// and N-HALF L2 BLOCKING: wg -> (half, m-row, n in 25) so each XCD sweeps a
// 2 MB Wb-half (L2-resident) instead of the full 3.9 MB.
// ---------------------------------------------------------------------------
__global__ __launch_bounds__(256) void k_xqm(const unsigned short* __restrict__ Ab,
        const unsigned short* __restrict__ Bb, const float* __restrict__ bq,
        const float* __restrict__ bv, unsigned short* __restrict__ xqb,
        unsigned short* __restrict__ xvb, int Mloc, int mtiles)
{
    __shared__ __attribute__((aligned(16))) char smem[65536];
    unsigned short (*Cs)[136] = (unsigned short (*)[136])smem;   // epilogue alias

    int nwg = 50 * mtiles;
    int bid = blockIdx.x;
    int q8 = nwg >> 3, r8 = nwg & 7;
    int xcd = bid & 7, idx = bid >> 3;
    int wg = (xcd < r8 ? xcd * (q8 + 1) : r8 * (q8 + 1) + (xcd - r8) * q8) + idx;
    // n-half blocking
    int halfSz = 25 * mtiles;
    int half = wg / halfSz;
    int rem  = wg - half * halfSz;
    int by = rem / 25;
    int bx = half * 25 + rem % 25;

    int t = threadIdx.x;
    int l = t & 63, w = t >> 6;
    int wm = w >> 1, wn = w & 1;
    int m0 = by * 128, n0 = bx * 128;
    int cl = l & 15, rh = l >> 4;

    int srow = l >> 3;                 // row&7 within chunk
    int sun  = (l & 7) ^ srow;         // inverse-swizzled source col-unit
    int sx = cl & 7;                   // fragment-read row&7

    f32x4 zero4 = {0.f, 0.f, 0.f, 0.f};
    f32x4 acc[4][4];
    #pragma unroll
    for (int a = 0; a < 4; ++a)
        #pragma unroll
        for (int bb = 0; bb < 4; ++bb) acc[a][bb] = zero4;

    #pragma unroll
    for (int i = 0; i < 4; ++i) {
        int c = w * 4 + i;
        int row = c * 8 + srow;
        gload_lds16(&Ab[(size_t)(m0 + row) * KP + 0 + sun * 8], smem + c * 1024);
        gload_lds16(&Bb[(size_t)(n0 + row) * KP + 0 + sun * 8], smem + 16384 + c * 1024);
    }
    __syncthreads();

    int cur = 0;
    #pragma unroll
    for (int step = 0; step < 5; ++step) {
        if (step < 4) {
            int k0 = (step + 1) * 64;
            char* nb = smem + (cur ^ 1) * 32768;
            #pragma unroll
            for (int i = 0; i < 4; ++i) {
                int c = w * 4 + i;
                int row = c * 8 + srow;
                gload_lds16(&Ab[(size_t)(m0 + row) * KP + k0 + sun * 8], nb + c * 1024);
                gload_lds16(&Bb[(size_t)(n0 + row) * KP + k0 + sun * 8], nb + 16384 + c * 1024);
            }
        }
        {
            unsigned short (*As)[64] = (unsigned short (*)[64])(smem + cur * 32768);
            unsigned short (*Bs)[64] = (unsigned short (*)[64])(smem + cur * 32768 + 16384);
            #pragma unroll
            for (int k2 = 0; k2 < 2; ++k2) {
                int ku = ((k2 * 4 + rh) ^ sx) * 8;
                short8 af[4], bf[4];
                #pragma unroll
                for (int f = 0; f < 4; ++f) {
                    af[f] = *(const short8*)&As[wm * 64 + f * 16 + cl][ku];
                    bf[f] = *(const short8*)&Bs[wn * 64 + f * 16 + cl][ku];
                }
                #pragma unroll
                for (int mf = 0; mf < 4; ++mf)
                    #pragma unroll
                    for (int nf = 0; nf < 4; ++nf)
                        acc[mf][nf] = __builtin_amdgcn_mfma_f32_16x16x32_bf16(
                            af[mf], bf[nf], acc[mf][nf], 0, 0, 0);
            }
        }
        __syncthreads();
        cur ^= 1;
    }

    #pragma unroll
    for (int nf = 0; nf < 4; ++nf) {
        int gn = n0 + wn * 64 + nf * 16 + cl;
        float bias = (gn < EQn) ? bq[gn] : bv[gn - EQn];
        #pragma unroll
        for (int mf = 0; mf < 4; ++mf) {
            int lrow = wm * 64 + mf * 16 + rh * 4;
            #pragma unroll
            for (int r = 0; r < 4; ++r)
                Cs[lrow + r][wn * 64 + nf * 16 + cl] = f2b(acc[mf][nf][r] + bias);
        }
    }
    __syncthreads();

    for (int ch = t; ch < 128 * 16; ch += 256) {
        int row = ch >> 4, colc = (ch & 15) * 8;
        int gm = m0 + row;
        short8 v = *(const short8*)&Cs[row][colc];
        int gn = n0 + colc;
        if (gn < EQn)
            __builtin_nontemporal_store(v, (short8*)&xqb[(size_t)gm * EQn + gn]);
        else
            __builtin_nontemporal_store(v, (short8*)&xvb[(size_t)gm * HDn + (gn - EQn)]);
    }
}

// ---------------------------------------------------------------------------
// k_attn v6: WAVE = HEAD, 5 blocks per bl. h2 output now bf16.
// ---------------------------------------------------------------------------
__global__ __launch_bounds__(256) void k_attn(const unsigned short* __restrict__ kT,
        const unsigned short* __restrict__ xqb, const unsigned short* __restrict__ xvb,
        unsigned short* __restrict__ h2b, int nwg)
{
    __shared__ __attribute__((aligned(16))) unsigned short kb[32 * KB];
    __shared__ float wmw[4][32 * 33];
    __shared__ float vmw[4][Sn * DHn];

    int t = threadIdx.x, l = t & 63, w = t >> 6;
    int cl = l & 15, rh = l >> 4;

    int bid = blockIdx.x;
    int q8 = nwg >> 3, r8 = nwg & 7;
    int xcd = bid & 7, idx = bid >> 3;
    int wg = (xcd < r8 ? xcd * (q8 + 1) : r8 * (q8 + 1) + (xcd - r8) * q8) + idx;
    int bl = wg / 5, hg = wg % 5;
    int h = hg * 4 + w;

    for (int p = t; p < 1312; p += 256)
        *(short8*)&kb[p * 8] = *(const short8*)&kT[(size_t)bl * (32 * KB) + p * 8];

    const unsigned short* vsrc = xvb + (size_t)bl * (Sn * HDn) + h * (Sn * DHn);
    for (int ch = l; ch < 75; ch += 64) {
        short8 v = *(const short8*)&vsrc[ch * 8];
        #pragma unroll
        for (int e = 0; e < 8; ++e) vmw[w][ch * 8 + e] = b2f((unsigned short)v[e]);
    }

    const unsigned short* qsrc = xqb + (size_t)bl * (Sn * EQn) + (size_t)h * (Sn * Dm);
    short8 aq[2][10];
    #pragma unroll
    for (int ti = 0; ti < 2; ++ti) {
        int row = ti * 16 + cl; if (row > 29) row = 29;
        const unsigned short* qrow = qsrc + row * Dm;
        #pragma unroll
        for (int ks = 0; ks < 9; ++ks)
            aq[ti][ks] = *(const short8*)&qrow[ks * 32 + rh * 8];
        short8 a9 = {0, 0, 0, 0, 0, 0, 0, 0};
        if (rh == 0) a9 = *(const short8*)&qrow[288];
        else if (rh == 1) {
            short4v lo = *(const short4v*)&qrow[296];
            a9[0] = lo.x; a9[1] = lo.y; a9[2] = lo.z; a9[3] = lo.w;
        }
        aq[ti][9] = a9;
    }
    __syncthreads();

    f32x4 zero4 = {0.f, 0.f, 0.f, 0.f};
    f32x4 acc[2][2] = {{zero4, zero4}, {zero4, zero4}};
    #pragma unroll
    for (int ks = 0; ks < 10; ++ks) {
        short8 b0 = *(const short8*)&kb[cl * KB + ks * 32 + rh * 8];
        short8 b1 = *(const short8*)&kb[(16 + cl) * KB + ks * 32 + rh * 8];
        #pragma unroll
        for (int ti = 0; ti < 2; ++ti) {
            acc[ti][0] = __builtin_amdgcn_mfma_f32_16x16x32_bf16(aq[ti][ks], b0, acc[ti][0], 0, 0, 0);
            acc[ti][1] = __builtin_amdgcn_mfma_f32_16x16x32_bf16(aq[ti][ks], b1, acc[ti][1], 0, 0, 0);
        }
    }

    float m0 = -1e30f, m1 = -1e30f;
    #pragma unroll
    for (int ti = 0; ti < 2; ++ti)
        #pragma unroll
        for (int r = 0; r < 4; ++r) {
            int i = ti * 16 + rh * 4 + r;
            if (i < Sn) { m0 = fmaxf(m0, acc[ti][0][r]); m1 = fmaxf(m1, acc[ti][1][r]); }
        }
    m0 = fmaxf(m0, __shfl_xor(m0, 16)); m0 = fmaxf(m0, __shfl_xor(m0, 32));
    m1 = fmaxf(m1, __shfl_xor(m1, 16)); m1 = fmaxf(m1, __shfl_xor(m1, 32));

    float e0[2][4], e1[2][4], s0 = 0.f, s1 = 0.f;
    #pragma unroll
    for (int ti = 0; ti < 2; ++ti)
        #pragma unroll
        for (int r = 0; r < 4; ++r) {
            int i = ti * 16 + rh * 4 + r;
            float v0 = 0.f, v1 = 0.f;
            if (i < Sn) {
                v0 = __expf(acc[ti][0][r] - m0);
                v1 = __expf(acc[ti][1][r] - m1);
            }
            e0[ti][r] = v0; e1[ti][r] = v1;
            s0 += v0; s1 += v1;
        }
    s0 += __shfl_xor(s0, 16); s0 += __shfl_xor(s0, 32);
    s1 += __shfl_xor(s1, 16); s1 += __shfl_xor(s1, 32);
    float inv0 = 1.f / s0, inv1 = 1.f / s1;

    #pragma unroll
    for (int ti = 0; ti < 2; ++ti)
        #pragma unroll
        for (int r = 0; r < 4; ++r) {
            int i = ti * 16 + rh * 4 + r;
            if (i < Sn) {
                wmw[w][i * 33 + cl] = e0[ti][r] * inv0;
                if (cl < 14) wmw[w][i * 33 + 16 + cl] = e1[ti][r] * inv1;
            }
        }

    for (int p = l; p < Sn * DHn; p += 64) {
        int i = p / DHn, k = p - i * DHn;
        float a = 0.f;
        #pragma unroll
        for (int j = 0; j < Sn; ++j) a += wmw[w][i * 33 + j] * vmw[w][j * DHn + k];
        h2b[(size_t)bl * (Sn * HDn) + h * (Sn * DHn) + p] = f2b(a);
    }
}

// ---------------------------------------------------------------------------
// k_pool v3: per bl. Stages bf16 h2 directly (no f32 buffer), MFMA score GEMM,
// softmax, weighted sum from bf16 h values.
// ---------------------------------------------------------------------------
__global__ __launch_bounds__(256) void k_pool(const unsigned short* __restrict__ h2b,
        const unsigned short* __restrict__ WVb, const float* __restrict__ bV,
        const float* __restrict__ wq2, const float* __restrict__ bq2,
        float* __restrict__ out, int b0)
{
    __shared__ __attribute__((aligned(16))) unsigned short hbf[32 * 424]; // 27136 B
    __shared__ float zp[4][32];
    __shared__ float psm[Sn];
    int bl = blockIdx.x, t = threadIdx.x;
    int l = t & 63, w = t >> 6;
    int cl = l & 15, rh = l >> 4;

    const unsigned short* hsrc = h2b + (size_t)bl * (Sn * HDn);
    for (int p = t; p < 32 * 424; p += 256) {
        int row = p / 424, col = p - row * 424;
        hbf[p] = (row < Sn && col < HDn) ? hsrc[row * HDn + col] : 0;
    }
    __syncthreads();

    float zacc[2][4] = {{0.f,0.f,0.f,0.f},{0.f,0.f,0.f,0.f}};
    for (int nt = w; nt < 13; nt += 4) {
        int u0 = nt * 16;
        f32x4 acc0 = {0.f,0.f,0.f,0.f}, acc1 = {0.f,0.f,0.f,0.f};
        const unsigned short* brow = &WVb[(size_t)(u0 + cl) * KWV];
        #pragma unroll
        for (int ks = 0; ks < 13; ++ks) {
            short8 b  = *(const short8*)&brow[ks * 32 + rh * 8];
            short8 a0 = *(const short8*)&hbf[cl * 424 + ks * 32 + rh * 8];
            short8 a1 = *(const short8*)&hbf[(16 + cl) * 424 + ks * 32 + rh * 8];
            acc0 = __builtin_amdgcn_mfma_f32_16x16x32_bf16(a0, b, acc0, 0, 0, 0);
            acc1 = __builtin_amdgcn_mfma_f32_16x16x32_bf16(a1, b, acc1, 0, 0, 0);
        }
        int u = u0 + cl;
        float bVu = (u < AHn) ? bV[u] : 0.f;
        float wqu = (u < AHn) ? wq2[u] : 0.f;
        #pragma unroll
        for (int r = 0; r < 4; ++r) {
            zacc[0][r] += tanhf(acc0[r] + bVu) * wqu;
            zacc[1][r] += tanhf(acc1[r] + bVu) * wqu;
        }
    }
    #pragma unroll
    for (int mt = 0; mt < 2; ++mt)
        #pragma unroll
        for (int r = 0; r < 4; ++r) {
            float v = zacc[mt][r];
            v += __shfl_xor(v, 1); v += __shfl_xor(v, 2);
            v += __shfl_xor(v, 4); v += __shfl_xor(v, 8);
            zacc[mt][r] = v;
        }
    if (cl == 0) {
        #pragma unroll
        for (int mt = 0; mt < 2; ++mt)
            #pragma unroll
            for (int r = 0; r < 4; ++r)
                zp[w][mt * 16 + rh * 4 + r] = zacc[mt][r];
    }
    __syncthreads();

    if (t == 0) {
        float b2 = bq2[0];
        float sc[Sn], mx = -1e30f;
        for (int s = 0; s < Sn; ++s) {
            sc[s] = zp[0][s] + zp[1][s] + zp[2][s] + zp[3][s] + b2;
            mx = fmaxf(mx, sc[s]);
        }
        float sum = 0.f;
        for (int s = 0; s < Sn; ++s) { float e = __expf(sc[s] - mx); psm[s] = e; sum += e; }
        float inv = 1.f / sum;
        for (int s = 0; s < Sn; ++s) psm[s] *= inv;
    }
    __syncthreads();
    for (int e = t; e < HDn; e += 256) {
        float z = 0.f;
        #pragma unroll
        for (int s = 0; s < Sn; ++s) z += psm[s] * b2f(hbf[s * 424 + e]);
        out[(size_t)(b0 + bl) * HDn + e] = z;
    }
}

// ---------------------------------------------------------------------------
extern "C" void kernel_launch(void* const* d_in, const int* in_sizes, int n_in,
                              void* d_out, int out_size, void* d_ws, size_t ws_size,
                              hipStream_t stream)
{
    const int*   x   = (const int*)d_in[0];
    const float* emb = (const float*)d_in[1];
    const float* Wq  = (const float*)d_in[2];
    const float* bq  = (const float*)d_in[3];
    const float* Wv  = (const float*)d_in[4];
    const float* bv  = (const float*)d_in[5];
    const float* WVm = (const float*)d_in[6];
    const float* bV  = (const float*)d_in[7];
    const float* wq2 = (const float*)d_in[8];
    const float* bq2 = (const float*)d_in[9];
    float* outp = (float*)d_out;

    const size_t wbBytes  = (size_t)NW * KP * 2;            // 4,096,000
    const size_t wvbBytes = (size_t)AHP * KWV * 2;          //   173,056
    size_t fixed = wbBytes + wvbBytes;
    size_t wrem = (ws_size > fixed) ? ws_size - fixed : 0;
    // per-b: cbf 19200 + xqb 360000 + xvb 24000 + kT 20992 + h2b 24000 = 448,192
    int CB = Bn;                                            // prefer ONE chunk
    while (CB > 64 && (size_t)CB * 448192ull > wrem) CB >>= 1;

    char* ws = (char*)d_ws;
    unsigned short* Wb  = (unsigned short*)(ws);
    unsigned short* WVb = (unsigned short*)(ws + wbBytes);
    char* wsc = ws + fixed;
    unsigned short* cbf = (unsigned short*)(wsc);
    unsigned short* xqb = (unsigned short*)(wsc + (size_t)CB * 19200ull);
    unsigned short* xvb = (unsigned short*)(wsc + (size_t)CB * 379200ull);
    unsigned short* kT  = (unsigned short*)(wsc + (size_t)CB * 403200ull);
    unsigned short* h2b = (unsigned short*)(wsc + (size_t)CB * 424192ull);

    k_cast_w<<<dim3(2048), dim3(256), 0, stream>>>(Wq, Wv, WVm, Wb, WVb);

    for (int b0 = 0; b0 < Bn; b0 += CB) {
        int nloc = (b0 + CB <= Bn) ? CB : (Bn - b0);
        int Mloc = nloc * Sn;
        int mtiles = (Mloc + 127) / 128;
        k_ckt<<<dim3(nloc), dim3(256), 0, stream>>>(x, emb, cbf, kT, b0);
        k_xqm<<<dim3(50 * mtiles), dim3(256), 0, stream>>>(cbf, Wb, bq, bv,
                                                           xqb, xvb, Mloc, mtiles);
        int nwg = nloc * 5;
        k_attn<<<dim3(nwg), dim3(256), 0, stream>>>(kT, xqb, xvb, h2b, nwg);
        k_pool<<<dim3(nloc), dim3(256), 0, stream>>>(h2b, WVb, bV, wq2, bq2, outp, b0);
    }
}

// Round 27
// 197.938 us; speedup vs baseline: 1.0624x; 1.0371x over previous
//
#include <hip/hip_runtime.h>
#include <hip/hip_bf16.h>

#define Bn  512
#define Sn  30
#define Dm  300
#define Hn  20
#define DHn 20
#define AHn 200
#define HDn 400
#define EQn 6000
#define KP  320           // GEMM K padded to 10*32
#define NW  6400          // N = 6000 (Wq) + 400 (Wv) = 50*128 exactly
#define KB  328           // kb/kT row stride (bf16)
#define CFS 304           // cf LDS row stride in k_ckt
#define AHP 208           // WV rows padded to 13*16
#define KWV 416           // WV cols padded to 13*32

typedef __attribute__((ext_vector_type(8))) short short8;
typedef __attribute__((ext_vector_type(4))) short short4v;
typedef __attribute__((ext_vector_type(4))) float f32x4;

__device__ __forceinline__ unsigned short f2b(float v) {
    __hip_bfloat16 h = __float2bfloat16(v);
    return *(unsigned short*)&h;
}
__device__ __forceinline__ float b2f(unsigned short u) {
    union { unsigned int i; float f; } cv; cv.i = ((unsigned int)u) << 16; return cv.f;
}
// async global->LDS, 16B per lane; dest = wave-uniform base + lane*16
__device__ __forceinline__ void gload_lds16(const void* g, void* l) {
    __builtin_amdgcn_global_load_lds(
        (__attribute__((address_space(1))) void*)(void*)(g),
        (__attribute__((address_space(3))) void*)(l), 16, 0, 0u);
}

// ---------------------------------------------------------------------------
// k_ckt: one block per bl. c = emb[x]+PE (bf16, LDS) -> cbf rows + kT transposed
// ---------------------------------------------------------------------------
__global__ __launch_bounds__(256) void k_ckt(const int* __restrict__ x,
        const float* __restrict__ emb, unsigned short* __restrict__ cbf,
        unsigned short* __restrict__ kT, int b0)
{
    __shared__ __attribute__((aligned(16))) unsigned short cf[Sn * CFS];
    int bl = blockIdx.x, t = threadIdx.x;

    for (int p = t; p < Sn * Dm; p += 256) {
        int s = p / Dm, d = p - s * Dm;
        int tok = x[(b0 + bl) * Sn + s];
        float dv = expf(-0.06140226914650789f * (float)(d >> 1));
        float ang = (float)s * dv;
        float val = emb[(size_t)tok * Dm + d] + ((d & 1) ? cosf(ang) : sinf(ang));
        cf[s * CFS + d] = f2b(val);
    }
    __syncthreads();

    for (int p = t; p < 30 * 40; p += 256) {
        int s = p / 40, un = p % 40, d0 = un * 8;
        short8 v = {0, 0, 0, 0, 0, 0, 0, 0};
        #pragma unroll
        for (int e = 0; e < 8; ++e) {
            int d = d0 + e;
            if (d < Dm) v[e] = (short)cf[s * CFS + d];
        }
        *(short8*)&cbf[(size_t)(bl * Sn + s) * KP + d0] = v;
    }

    for (int p = t; p < 1312; p += 256) {
        int j = p / 41, ch = p % 41, d0 = ch * 8;
        short8 v = {0, 0, 0, 0, 0, 0, 0, 0};
        if (j < Sn) {
            #pragma unroll
            for (int e = 0; e < 8; ++e) {
                int d = d0 + e;
                if (d < Dm) {
                    int f = d * Sn + j;
                    v[e] = (short)cf[(f / Dm) * CFS + (f % Dm)];
                }
            }
        }
        *(short8*)&kT[(size_t)bl * (32 * KB) + j * KB + d0] = v;
    }
}

// ---------------------------------------------------------------------------
// k_cast_w: Wb[NW][KP] = bf16([Wq; Wv]); WVb[AHP][KWV] = bf16(WV), zero-padded
// ---------------------------------------------------------------------------
__global__ __launch_bounds__(256) void k_cast_w(const float* __restrict__ Wq,
        const float* __restrict__ Wv, const float* __restrict__ WVm,
        unsigned short* __restrict__ Wb, unsigned short* __restrict__ WVb)
{
    int total = NW * KP + AHP * KWV;
    for (int p = blockIdx.x * 256 + threadIdx.x; p < total; p += gridDim.x * 256) {
        if (p < NW * KP) {
            int nq = p / KP, k = p - nq * KP;
            float v = 0.f;
            if (k < Dm)
                v = (nq < EQn) ? Wq[(size_t)nq * Dm + k]
                               : Wv[(size_t)(nq - EQn) * Dm + k];
            Wb[p] = f2b(v);
        } else {
            int q = p - NW * KP;
            int u = q / KWV, k = q - u * KWV;
            float v = (u < AHn && k < HDn) ? WVm[(size_t)u * HDn + k] : 0.f;
            WVb[q] = f2b(v);
        }
    }
}

// ---------------------------------------------------------------------------
// k_xqm v8: 128x128 tile, 8 WAVES (512 thr), BK=64 dbuf, both-sides XOR
// swizzle, n-half L2 blocking, nt-stores. Per-wave output 64x32 (acc 4x2).
// 64 KB LDS -> 2 blocks/CU x 8 waves = 16 waves/CU.
// ---------------------------------------------------------------------------
__global__ __launch_bounds__(512) void k_xqm(const unsigned short* __restrict__ Ab,
        const unsigned short* __restrict__ Bb, const float* __restrict__ bq,
        const float* __restrict__ bv, unsigned short* __restrict__ xqb,
        unsigned short* __restrict__ xvb, int Mloc, int mtiles)
{
    __shared__ __attribute__((aligned(16))) char smem[65536];
    unsigned short (*Cs)[136] = (unsigned short (*)[136])smem;   // epilogue alias

    int nwg = 50 * mtiles;
    int bid = blockIdx.x;
    int q8 = nwg >> 3, r8 = nwg & 7;
    int xcd = bid & 7, idx = bid >> 3;
    int wg = (xcd < r8 ? xcd * (q8 + 1) : r8 * (q8 + 1) + (xcd - r8) * q8) + idx;
    int halfSz = 25 * mtiles;
    int half = wg / halfSz;
    int rem  = wg - half * halfSz;
    int by = rem / 25;
    int bx = half * 25 + rem % 25;

    int t = threadIdx.x;
    int l = t & 63, w = t >> 6;          // 8 waves
    int wm = w >> 2, wn = w & 3;         // wave tile: 64 rows x 32 cols
    int m0 = by * 128, n0 = bx * 128;
    int cl = l & 15, rh = l >> 4;

    int srow = l >> 3;                 // row&7 within chunk
    int sun  = (l & 7) ^ srow;         // inverse-swizzled source col-unit
    int sx = cl & 7;                   // fragment-read row&7

    f32x4 zero4 = {0.f, 0.f, 0.f, 0.f};
    f32x4 acc[4][2];
    #pragma unroll
    for (int a = 0; a < 4; ++a)
        #pragma unroll
        for (int bb = 0; bb < 2; ++bb) acc[a][bb] = zero4;

    // prologue: stage k-step 0 into buf 0 (wave w: chunks 2w, 2w+1 of A and B)
    #pragma unroll
    for (int i = 0; i < 2; ++i) {
        int c = w * 2 + i;
        int row = c * 8 + srow;
        gload_lds16(&Ab[(size_t)(m0 + row) * KP + 0 + sun * 8], smem + c * 1024);
        gload_lds16(&Bb[(size_t)(n0 + row) * KP + 0 + sun * 8], smem + 16384 + c * 1024);
    }
    __syncthreads();

    int cur = 0;
    #pragma unroll
    for (int step = 0; step < 5; ++step) {
        if (step < 4) {
            int k0 = (step + 1) * 64;
            char* nb = smem + (cur ^ 1) * 32768;
            #pragma unroll
            for (int i = 0; i < 2; ++i) {
                int c = w * 2 + i;
                int row = c * 8 + srow;
                gload_lds16(&Ab[(size_t)(m0 + row) * KP + k0 + sun * 8], nb + c * 1024);
                gload_lds16(&Bb[(size_t)(n0 + row) * KP + k0 + sun * 8], nb + 16384 + c * 1024);
            }
        }
        {
            unsigned short (*As)[64] = (unsigned short (*)[64])(smem + cur * 32768);
            unsigned short (*Bs)[64] = (unsigned short (*)[64])(smem + cur * 32768 + 16384);
            #pragma unroll
            for (int k2 = 0; k2 < 2; ++k2) {
                int ku = ((k2 * 4 + rh) ^ sx) * 8;
                short8 af[4], bf[2];
                #pragma unroll
                for (int f = 0; f < 4; ++f)
                    af[f] = *(const short8*)&As[wm * 64 + f * 16 + cl][ku];
                #pragma unroll
                for (int f = 0; f < 2; ++f)
                    bf[f] = *(const short8*)&Bs[wn * 32 + f * 16 + cl][ku];
                #pragma unroll
                for (int mf = 0; mf < 4; ++mf)
                    #pragma unroll
                    for (int nf = 0; nf < 2; ++nf)
                        acc[mf][nf] = __builtin_amdgcn_mfma_f32_16x16x32_bf16(
                            af[mf], bf[nf], acc[mf][nf], 0, 0, 0);
            }
        }
        __syncthreads();
        cur ^= 1;
    }

    // epilogue 1: acc -> Cs bf16 (C/D map col=lane&15, row=(lane>>4)*4+reg)
    #pragma unroll
    for (int nf = 0; nf < 2; ++nf) {
        int gn = n0 + wn * 32 + nf * 16 + cl;
        float bias = (gn < EQn) ? bq[gn] : bv[gn - EQn];
        #pragma unroll
        for (int mf = 0; mf < 4; ++mf) {
            int lrow = wm * 64 + mf * 16 + rh * 4;
            #pragma unroll
            for (int r = 0; r < 4; ++r)
                Cs[lrow + r][wn * 32 + nf * 16 + cl] = f2b(acc[mf][nf][r] + bias);
        }
    }
    __syncthreads();

    // epilogue 2: coalesced non-temporal stores
    for (int ch = t; ch < 128 * 16; ch += 512) {
        int row = ch >> 4, colc = (ch & 15) * 8;
        int gm = m0 + row;
        short8 v = *(const short8*)&Cs[row][colc];
        int gn = n0 + colc;
        if (gn < EQn)
            __builtin_nontemporal_store(v, (short8*)&xqb[(size_t)gm * EQn + gn]);
        else
            __builtin_nontemporal_store(v, (short8*)&xvb[(size_t)gm * HDn + (gn - EQn)]);
    }
}

// ---------------------------------------------------------------------------
// k_attn v6: WAVE = HEAD, 5 blocks per bl. h2 output bf16.
// ---------------------------------------------------------------------------
__global__ __launch_bounds__(256) void k_attn(const unsigned short* __restrict__ kT,
        const unsigned short* __restrict__ xqb, const unsigned short* __restrict__ xvb,
        unsigned short* __restrict__ h2b, int nwg)
{
    __shared__ __attribute__((aligned(16))) unsigned short kb[32 * KB];
    __shared__ float wmw[4][32 * 33];
    __shared__ float vmw[4][Sn * DHn];

    int t = threadIdx.x, l = t & 63, w = t >> 6;
    int cl = l & 15, rh = l >> 4;

    int bid = blockIdx.x;
    int q8 = nwg >> 3, r8 = nwg & 7;
    int xcd = bid & 7, idx = bid >> 3;
    int wg = (xcd < r8 ? xcd * (q8 + 1) : r8 * (q8 + 1) + (xcd - r8) * q8) + idx;
    int bl = wg / 5, hg = wg % 5;
    int h = hg * 4 + w;

    for (int p = t; p < 1312; p += 256)
        *(short8*)&kb[p * 8] = *(const short8*)&kT[(size_t)bl * (32 * KB) + p * 8];

    const unsigned short* vsrc = xvb + (size_t)bl * (Sn * HDn) + h * (Sn * DHn);
    for (int ch = l; ch < 75; ch += 64) {
        short8 v = *(const short8*)&vsrc[ch * 8];
        #pragma unroll
        for (int e = 0; e < 8; ++e) vmw[w][ch * 8 + e] = b2f((unsigned short)v[e]);
    }

    const unsigned short* qsrc = xqb + (size_t)bl * (Sn * EQn) + (size_t)h * (Sn * Dm);
    short8 aq[2][10];
    #pragma unroll
    for (int ti = 0; ti < 2; ++ti) {
        int row = ti * 16 + cl; if (row > 29) row = 29;
        const unsigned short* qrow = qsrc + row * Dm;
        #pragma unroll
        for (int ks = 0; ks < 9; ++ks)
            aq[ti][ks] = *(const short8*)&qrow[ks * 32 + rh * 8];
        short8 a9 = {0, 0, 0, 0, 0, 0, 0, 0};
        if (rh == 0) a9 = *(const short8*)&qrow[288];
        else if (rh == 1) {
            short4v lo = *(const short4v*)&qrow[296];
            a9[0] = lo.x; a9[1] = lo.y; a9[2] = lo.z; a9[3] = lo.w;
        }
        aq[ti][9] = a9;
    }
    __syncthreads();

    f32x4 zero4 = {0.f, 0.f, 0.f, 0.f};
    f32x4 acc[2][2] = {{zero4, zero4}, {zero4, zero4}};
    #pragma unroll
    for (int ks = 0; ks < 10; ++ks) {
        short8 b0 = *(const short8*)&kb[cl * KB + ks * 32 + rh * 8];
        short8 b1 = *(const short8*)&kb[(16 + cl) * KB + ks * 32 + rh * 8];
        #pragma unroll
        for (int ti = 0; ti < 2; ++ti) {
            acc[ti][0] = __builtin_amdgcn_mfma_f32_16x16x32_bf16(aq[ti][ks], b0, acc[ti][0], 0, 0, 0);
            acc[ti][1] = __builtin_amdgcn_mfma_f32_16x16x32_bf16(aq[ti][ks], b1, acc[ti][1], 0, 0, 0);
        }
    }

    float m0 = -1e30f, m1 = -1e30f;
    #pragma unroll
    for (int ti = 0; ti < 2; ++ti)
        #pragma unroll
        for (int r = 0; r < 4; ++r) {
            int i = ti * 16 + rh * 4 + r;
            if (i < Sn) { m0 = fmaxf(m0, acc[ti][0][r]); m1 = fmaxf(m1, acc[ti][1][r]); }
        }
    m0 = fmaxf(m0, __shfl_xor(m0, 16)); m0 = fmaxf(m0, __shfl_xor(m0, 32));
    m1 = fmaxf(m1, __shfl_xor(m1, 16)); m1 = fmaxf(m1, __shfl_xor(m1, 32));

    float e0[2][4], e1[2][4], s0 = 0.f, s1 = 0.f;
    #pragma unroll
    for (int ti = 0; ti < 2; ++ti)
        #pragma unroll
        for (int r = 0; r < 4; ++r) {
            int i = ti * 16 + rh * 4 + r;
            float v0 = 0.f, v1 = 0.f;
            if (i < Sn) {
                v0 = __expf(acc[ti][0][r] - m0);
                v1 = __expf(acc[ti][1][r] - m1);
            }
            e0[ti][r] = v0; e1[ti][r] = v1;
            s0 += v0; s1 += v1;
        }
    s0 += __shfl_xor(s0, 16); s0 += __shfl_xor(s0, 32);
    s1 += __shfl_xor(s1, 16); s1 += __shfl_xor(s1, 32);
    float inv0 = 1.f / s0, inv1 = 1.f / s1;

    #pragma unroll
    for (int ti = 0; ti < 2; ++ti)
        #pragma unroll
        for (int r = 0; r < 4; ++r) {
            int i = ti * 16 + rh * 4 + r;
            if (i < Sn) {
                wmw[w][i * 33 + cl] = e0[ti][r] * inv0;
                if (cl < 14) wmw[w][i * 33 + 16 + cl] = e1[ti][r] * inv1;
            }
        }

    for (int p = l; p < Sn * DHn; p += 64) {
        int i = p / DHn, k = p - i * DHn;
        float a = 0.f;
        #pragma unroll
        for (int j = 0; j < Sn; ++j) a += wmw[w][i * 33 + j] * vmw[w][j * DHn + k];
        h2b[(size_t)bl * (Sn * HDn) + h * (Sn * DHn) + p] = f2b(a);
    }
}

// ---------------------------------------------------------------------------
// k_pool v3: per bl. Stages bf16 h2 directly, MFMA score GEMM, softmax,
// weighted sum from bf16 h values. (R26-verified)
// ---------------------------------------------------------------------------
__global__ __launch_bounds__(256) void k_pool(const unsigned short* __restrict__ h2b,
        const unsigned short* __restrict__ WVb, const float* __restrict__ bV,
        const float* __restrict__ wq2, const float* __restrict__ bq2,
        float* __restrict__ out, int b0)
{
    __shared__ __attribute__((aligned(16))) unsigned short hbf[32 * 424];
    __shared__ float zp[4][32];
    __shared__ float psm[Sn];
    int bl = blockIdx.x, t = threadIdx.x;
    int l = t & 63, w = t >> 6;
    int cl = l & 15, rh = l >> 4;

    const unsigned short* hsrc = h2b + (size_t)bl * (Sn * HDn);
    for (int p = t; p < 32 * 424; p += 256) {
        int row = p / 424, col = p - row * 424;
        hbf[p] = (row < Sn && col < HDn) ? hsrc[row * HDn + col] : 0;
    }
    __syncthreads();

    float zacc[2][4] = {{0.f,0.f,0.f,0.f},{0.f,0.f,0.f,0.f}};
    for (int nt = w; nt < 13; nt += 4) {
        int u0 = nt * 16;
        f32x4 acc0 = {0.f,0.f,0.f,0.f}, acc1 = {0.f,0.f,0.f,0.f};
        const unsigned short* brow = &WVb[(size_t)(u0 + cl) * KWV];
        #pragma unroll
        for (int ks = 0; ks < 13; ++ks) {
            short8 b  = *(const short8*)&brow[ks * 32 + rh * 8];
            short8 a0 = *(const short8*)&hbf[cl * 424 + ks * 32 + rh * 8];
            short8 a1 = *(const short8*)&hbf[(16 + cl) * 424 + ks * 32 + rh * 8];
            acc0 = __builtin_amdgcn_mfma_f32_16x16x32_bf16(a0, b, acc0, 0, 0, 0);
            acc1 = __builtin_amdgcn_mfma_f32_16x16x32_bf16(a1, b, acc1, 0, 0, 0);
        }
        int u = u0 + cl;
        float bVu = (u < AHn) ? bV[u] : 0.f;
        float wqu = (u < AHn) ? wq2[u] : 0.f;
        #pragma unroll
        for (int r = 0; r < 4; ++r) {
            zacc[0][r] += tanhf(acc0[r] + bVu) * wqu;
            zacc[1][r] += tanhf(acc1[r] + bVu) * wqu;
        }
    }
    #pragma unroll
    for (int mt = 0; mt < 2; ++mt)
        #pragma unroll
        for (int r = 0; r < 4; ++r) {
            float v = zacc[mt][r];
            v += __shfl_xor(v, 1); v += __shfl_xor(v, 2);
            v += __shfl_xor(v, 4); v += __shfl_xor(v, 8);
            zacc[mt][r] = v;
        }
    if (cl == 0) {
        #pragma unroll
        for (int mt = 0; mt < 2; ++mt)
            #pragma unroll
            for (int r = 0; r < 4; ++r)
                zp[w][mt * 16 + rh * 4 + r] = zacc[mt][r];
    }
    __syncthreads();

    if (t == 0) {
        float b2 = bq2[0];
        float sc[Sn], mx = -1e30f;
        for (int s = 0; s < Sn; ++s) {
            sc[s] = zp[0][s] + zp[1][s] + zp[2][s] + zp[3][s] + b2;
            mx = fmaxf(mx, sc[s]);
        }
        float sum = 0.f;
        for (int s = 0; s < Sn; ++s) { float e = __expf(sc[s] - mx); psm[s] = e; sum += e; }
        float inv = 1.f / sum;
        for (int s = 0; s < Sn; ++s) psm[s] *= inv;
    }
    __syncthreads();
    for (int e = t; e < HDn; e += 256) {
        float z = 0.f;
        #pragma unroll
        for (int s = 0; s < Sn; ++s) z += psm[s] * b2f(hbf[s * 424 + e]);
        out[(size_t)(b0 + bl) * HDn + e] = z;
    }
}

// ---------------------------------------------------------------------------
extern "C" void kernel_launch(void* const* d_in, const int* in_sizes, int n_in,
                              void* d_out, int out_size, void* d_ws, size_t ws_size,
                              hipStream_t stream)
{
    const int*   x   = (const int*)d_in[0];
    const float* emb = (const float*)d_in[1];
    const float* Wq  = (const float*)d_in[2];
    const float* bq  = (const float*)d_in[3];
    const float* Wv  = (const float*)d_in[4];
    const float* bv  = (const float*)d_in[5];
    const float* WVm = (const float*)d_in[6];
    const float* bV  = (const float*)d_in[7];
    const float* wq2 = (const float*)d_in[8];
    const float* bq2 = (const float*)d_in[9];
    float* outp = (float*)d_out;

    const size_t wbBytes  = (size_t)NW * KP * 2;            // 4,096,000
    const size_t wvbBytes = (size_t)AHP * KWV * 2;          //   173,056
    size_t fixed = wbBytes + wvbBytes;
    size_t wrem = (ws_size > fixed) ? ws_size - fixed : 0;
    // per-b: cbf 19200 + xqb 360000 + xvb 24000 + kT 20992 + h2b 24000 = 448,192
    int CB = Bn;
    while (CB > 64 && (size_t)CB * 448192ull > wrem) CB >>= 1;

    char* ws = (char*)d_ws;
    unsigned short* Wb  = (unsigned short*)(ws);
    unsigned short* WVb = (unsigned short*)(ws + wbBytes);
    char* wsc = ws + fixed;
    unsigned short* cbf = (unsigned short*)(wsc);
    unsigned short* xqb = (unsigned short*)(wsc + (size_t)CB * 19200ull);
    unsigned short* xvb = (unsigned short*)(wsc + (size_t)CB * 379200ull);
    unsigned short* kT  = (unsigned short*)(wsc + (size_t)CB * 403200ull);
    unsigned short* h2b = (unsigned short*)(wsc + (size_t)CB * 424192ull);

    k_cast_w<<<dim3(2048), dim3(256), 0, stream>>>(Wq, Wv, WVm, Wb, WVb);

    for (int b0 = 0; b0 < Bn; b0 += CB) {
        int nloc = (b0 + CB <= Bn) ? CB : (Bn - b0);
        int Mloc = nloc * Sn;
        int mtiles = (Mloc + 127) / 128;
        k_ckt<<<dim3(nloc), dim3(256), 0, stream>>>(x, emb, cbf, kT, b0);
        k_xqm<<<dim3(50 * mtiles), dim3(512), 0, stream>>>(cbf, Wb, bq, bv,
                                                           xqb, xvb, Mloc, mtiles);
        int nwg = nloc * 5;
        k_attn<<<dim3(nwg), dim3(256), 0, stream>>>(kT, xqb, xvb, h2b, nwg);
        k_pool<<<dim3(nloc), dim3(256), 0, stream>>>(h2b, WVb, bV, wq2, bq2, outp, b0);
    }
}